// Round 14
// baseline (79.975 us; speedup 1.0000x reference)
//
#include <hip/hip_runtime.h>

// CRF log-likelihood, B=128, T=2048, K=96 on gfx950.
//
// Chunked-parallel forward algorithm (verified R3/R4/R5/R10/R12/R13): logZ
// telescopes into per-chunk Phi differences; exp(trans) contracts normalized
// alpha at Hilbert rate ~0.36/step; chunks warm up from a fabricated init
// WARM=8 steps early (clamped at 0). Geometry (R12): CHUNKS=128, CLEN=16,
// 1024 one-wave blocks, renorm every 2nd step.
//
// Round 14: R13 (3-slab DMA lead) was NEUTRAL -> latency hiding is not the
// constraint; DRAM PAGE LOCALITY is. Per-step loads were 16 streams x 384B
// (768KB apart) -> page-activate-bound ~1.7 TB/s (streaming kernels hit
// 7 TB/s on the same chip). Fix: 4-step SUPERSLABS - 1536B contiguous per
// batch row per burst (4x fewer page activates), via the R13-verified
// global_load_lds + counted-vmcnt + XOR-swizzle mechanics:
//   ring of 2 x 24KB superslabs; 24 dma16 each; wait vmcnt(24);
//   tail/dummy issues target the just-consumed (dead) buffer;
//   per-lane address clamp at the input's end handles the T boundary;
//   source swizzle x ^= ((row&7)<<4) with row = 2m+dr (m = row pair).

constexpr int K      = 96;
constexpr int NB     = 16;   // batches per wave (MFMA N dim)
constexpr int CHUNKS = 128;
constexpr int CLEN   = 16;   // accumulated steps per chunk
constexpr int WARM   = 8;    // warm-up steps (clamped at t=0)
constexpr int B      = 128;
constexpr int SS     = 4;    // steps per superslab

typedef __attribute__((ext_vector_type(8))) short bf16x8;
typedef __attribute__((ext_vector_type(4))) float f32x4;

__device__ __forceinline__ unsigned short f2bf(float f) {
  unsigned int b = __float_as_uint(f);
  return (unsigned short)((b + 0x7fff + ((b >> 16) & 1)) >> 16);  // RNE
}
__device__ __forceinline__ float bf2f(unsigned short h) {
  return __uint_as_float(((unsigned int)h) << 16);
}
__device__ __forceinline__ unsigned int cvt_pk_bf16(float lo, float hi) {
  unsigned int r;
  asm volatile("v_cvt_pk_bf16_f32 %0, %1, %2" : "=v"(r) : "v"(lo), "v"(hi));
  return r;
}
__device__ __forceinline__ float lane_bcast(int addr4, float v) {
  return __int_as_float(__builtin_amdgcn_ds_bpermute(addr4, __float_as_int(v)));
}
__device__ __forceinline__ void dma16(const void* g, void* l) {
  __builtin_amdgcn_global_load_lds(
      (const __attribute__((address_space(1))) void*)g,
      (__attribute__((address_space(3))) void*)l, 16, 0, 0);
}

__global__ __launch_bounds__(64, 1) void crf_fwd_chunk(
    const float* __restrict__ inp,    // [B,T,K]
    const int*   __restrict__ tags,   // [B,T]
    const int*   __restrict__ mask,   // [B,T]
    const float* __restrict__ trans,  // [K,K]
    float* __restrict__ pden,         // [CHUNKS][B]
    float* __restrict__ pnum,         // [CHUNKS][B]
    float* __restrict__ pcnt,         // [CHUNKS][B]
    int T)
{
  const int l  = threadIdx.x;
  const int bl = l & 15;     // batch-in-group (= MFMA col)
  const int hi = l >> 4;
  const int g  = blockIdx.x;
  const int c  = blockIdx.y;
  const int b  = g * NB + bl;
  const int bcast = bl * 4;

  const int s_init = max(0, c * CLEN - WARM);
  const int s_A    = c * CLEN;
  const int s_end  = min(c * CLEN + CLEN, T - 1);

  __shared__ unsigned short Xs[NB][104];          // bf16 state
  __shared__ char Ering[2][NB * SS * K * 4];      // 2 x 24KB superslabs

  // A fragments: A[row=j][k=i] = exp(trans[i][j]); row=lane&15, k=(lane>>4)*8+e
  bf16x8 A[6][3];
  #pragma unroll
  for (int jt = 0; jt < 6; ++jt) {
    #pragma unroll
    for (int kf = 0; kf < 3; ++kf) {
      const int j = jt * 16 + bl;
      #pragma unroll
      for (int e = 0; e < 8; ++e) {
        const int i = kf * 32 + hi * 8 + e;
        A[jt][kf][e] = (short)f2bf(__expf(trans[i * K + j]));
      }
    }
  }

  const float* ib  = inp  + (size_t)b * T * K;
  const int*   mb  = mask + (size_t)b * T;
  const int*   tgb = tags + (size_t)b * T;

  // ---- init at s_init: x = exp(emit - emit[0]) (plain loads, pre-drain) ----
  {
    const float* i0 = ib + (size_t)s_init * K;
    float4 e0[6];
    #pragma unroll
    for (int jt = 0; jt < 6; ++jt) {
      float4 v = *(const float4*)(i0 + jt * 16 + hi * 4);
      v.x = __expf(v.x); v.y = __expf(v.y); v.z = __expf(v.z); v.w = __expf(v.w);
      e0[jt] = v;
    }
    const float r0  = lane_bcast(bcast, e0[0].x);
    const float inv = 1.0f / r0;
    #pragma unroll
    for (int jt = 0; jt < 6; ++jt) {
      uint2 p;
      p.x = cvt_pk_bf16(e0[jt].x * inv, e0[jt].y * inv);
      p.y = cvt_pk_bf16(e0[jt].z * inv, e0[jt].w * inv);
      *(uint2*)&Xs[bl][jt * 16 + hi * 4] = p;
    }
  }
  double Mref = (double)ib[(size_t)s_init * K];

  bf16x8 Bf[3];
  #pragma unroll
  for (int kf = 0; kf < 3; ++kf)
    Bf[kf] = *(const bf16x8*)&Xs[bl][kf * 32 + hi * 8];

  // mask bits for the whole chunk (<= 24 steps) — loop stays VMEM-free
  unsigned mbits = 0;
  const int nsteps = s_end - s_init;
  #pragma unroll
  for (int k2 = 0; k2 < CLEN + WARM; ++k2)
    if (k2 < nsteps)
      mbits |= (mb[s_init + 1 + k2] != 0 ? 1u : 0u) << k2;

  // Per-lane DMA geometry. Superslab LDS layout: [row r 0..15][1536B], where
  // row r's 1536B = steps s0..s0+3 of batch g*16+r, stored with byte offset
  // x holding global offset x ^ ((r&7)<<4) (inverse swizzle; read side XORs
  // the same). dma j=3m+p writes LDS [j*1024, j*1024+1024): per-lane
  // q = j*1024 + l*16 -> r = 2m+dr, x = q - r*1536, with (dr, x) lane consts.
  int drp[3], xp[3];
  const char* rb[3];   // row base (excl. swizzle, excl. m/s0 terms)
  #pragma unroll
  for (int p = 0; p < 3; ++p) {
    const int q = p * 1024 + l * 16;
    drp[p] = q / 1536;
    xp[p]  = q - drp[p] * 1536;
    rb[p]  = (const char*)(inp + (size_t)(g * 16 + drp[p]) * T * K);
  }
  const size_t rowpair = (size_t)2 * T * K * 4;
  const char* lim = (const char*)inp + (size_t)B * T * K * 4 - 16;
  const int swr = (bl & 7) << 4;   // read-side swizzle for row bl

  // drain compiler-scheduled VMEM: counted vmcnt is exact from here
  asm volatile("s_waitcnt vmcnt(0)" ::: "memory");
  __builtin_amdgcn_sched_barrier(0);

  auto issue_super = [&](int kk) {   // superslab kk covers steps s0..s0+3
    const int s0 = s_init + 1 + SS * kk;
    char* dst = &Ering[kk & 1][0];
    #pragma unroll
    for (int m = 0; m < 8; ++m) {
      #pragma unroll
      for (int p = 0; p < 3; ++p) {
        const int sw = ((2 * m + drp[p]) & 7) << 4;
        const char* src = rb[p] + (size_t)m * rowpair
                        + (size_t)s0 * (K * 4) + (xp[p] ^ sw);
        if (src > lim) src = lim;              // tail clamp (dummy-safe)
        dma16(src, dst + (m * 3 + p) * 1024);
      }
    }
  };

  // prologue: 2 superslabs in flight (48 loads)
  issue_super(0);
  issue_super(1);

  auto dostep = [&](int s, const char* slab, int u) {
    float4 xe[6];
    #pragma unroll
    for (int jt = 0; jt < 6; ++jt) {
      const float4 e4 = *(const float4*)(
          slab + bl * 1536 + u * 384 + ((jt * 64 + hi * 16) ^ swr));
      xe[jt].x = __expf(e4.x); xe[jt].y = __expf(e4.y);
      xe[jt].z = __expf(e4.z); xe[jt].w = __expf(e4.w);
    }
    f32x4 acc[6];
    #pragma unroll
    for (int jt = 0; jt < 6; ++jt) {
      f32x4 a = {0.f, 0.f, 0.f, 0.f};
      a = __builtin_amdgcn_mfma_f32_16x16x32_bf16(A[jt][0], Bf[0], a, 0, 0, 0);
      a = __builtin_amdgcn_mfma_f32_16x16x32_bf16(A[jt][1], Bf[1], a, 0, 0, 0);
      a = __builtin_amdgcn_mfma_f32_16x16x32_bf16(A[jt][2], Bf[2], a, 0, 0, 0);
      acc[jt] = a;
    }
    const bool mm = ((mbits >> (s - s_init - 1)) & 1u) != 0u;
    const bool renorm = (((s - s_init) & 1) == 0);
    float inv = 1.0f;
    if (renorm) {
      const float r = lane_bcast(bcast, acc[0][0]);   // C[0][b]
      inv = 1.0f / r;
      if (mm) Mref += (double)__logf(r);
    }
    if (mm) {   // masked steps keep old x
      #pragma unroll
      for (int jt = 0; jt < 6; ++jt) {
        uint2 p;
        p.x = cvt_pk_bf16(acc[jt][0] * inv * xe[jt].x,
                          acc[jt][1] * inv * xe[jt].y);
        p.y = cvt_pk_bf16(acc[jt][2] * inv * xe[jt].z,
                          acc[jt][3] * inv * xe[jt].w);
        *(uint2*)&Xs[bl][jt * 16 + hi * 4] = p;
      }
    }
    #pragma unroll
    for (int kf = 0; kf < 3; ++kf)
      Bf[kf] = *(const bf16x8*)&Xs[bl][kf * 32 + hi * 8];
  };

  auto phi = [&]() -> double {
    float sum = 0.f;
    #pragma unroll
    for (int u = 0; u < 24; ++u) sum += bf2f(Xs[bl][hi * 24 + u]);
    sum += __shfl_xor(sum, 16);
    sum += __shfl_xor(sum, 32);
    return Mref + (double)__logf(sum);
  };

  double phiA = 0.0;   // c==0: Phi before chunk is 0 by construction
  const int nss = (nsteps + SS - 1) / SS;   // superslabs (6 / 4 / 6-partial)
  for (int k = 0; k < nss; ++k) {
    // outstanding = 48 here -> vmcnt(24) == superslab k landed
    asm volatile("s_waitcnt vmcnt(24)" ::: "memory");
    __builtin_amdgcn_sched_barrier(0);
    const char* slab = &Ering[k & 1][0];
    const int s0 = s_init + 1 + SS * k;
    #pragma unroll
    for (int u = 0; u < SS; ++u) {
      const int s = s0 + u;
      if (s <= s_end) {
        dostep(s, slab, u);
        if (s == s_A) phiA = phi();
      }
    }
    // refill: (k+2)&1 == k&1 -> targets the just-consumed (dead) buffer;
    // beyond-range issues are clamped dummies keeping issue rate constant
    __builtin_amdgcn_sched_barrier(0);
    issue_super(k + 2);
    __builtin_amdgcn_sched_barrier(0);
  }
  const double phiB = phi();

  if (hi == 0) pden[c * B + b] = (float)(phiB - phiA);

  // ---- fused numerator: gold-path terms for t in [c*CLEN, c*CLEN+CLEN) ----
  const int t0 = c * CLEN;
  float nacc = 0.f, mcnt = 0.f;
  #pragma unroll
  for (int k = 0; k < CLEN / 4; ++k) {
    const int t  = t0 + 4 * k + hi;
    const int mt = mb[t];
    mcnt += (float)mt;
    if (t < T - 1) {
      const int tg  = tgb[t];
      const int tg1 = tgb[t + 1];
      nacc = fmaf(trans[tg * K + tg1], (float)mb[t + 1], nacc);
      nacc = fmaf(ib[(size_t)t * K + tg], (float)mt, nacc);
    }
  }
  nacc += __shfl_xor(nacc, 16); nacc += __shfl_xor(nacc, 32);
  mcnt += __shfl_xor(mcnt, 16); mcnt += __shfl_xor(mcnt, 32);
  if (hi == 0) {
    pnum[c * B + b] = nacc;
    pcnt[c * B + b] = mcnt;
  }
}

// ---------------- final reduce: last-tag gather + sum ----------------
__global__ __launch_bounds__(128) void crf_reduce(
    const float* __restrict__ inp, const int* __restrict__ tags,
    const int* __restrict__ mask,
    const float* __restrict__ pden, const float* __restrict__ pnum,
    const float* __restrict__ pcnt, float* __restrict__ out, int T)
{
  const int b = threadIdx.x;   // 128 = B
  float den = 0.f, num = 0.f, cnt = 0.f;
  for (int c = 0; c < CHUNKS; ++c) {
    den += pden[c * B + b];
    num += pnum[c * B + b];
    cnt += pcnt[c * B + b];
  }
  const int last_idx = (int)cnt - 1;
  float last_sc = 0.f;
  if (last_idx >= 0) {
    const int lt = tags[(size_t)b * T + last_idx];
    last_sc = inp[((size_t)b * T + (T - 1)) * K + lt]
            * (float)mask[(size_t)b * T + T - 1];
  }
  __shared__ float red[128];
  red[b] = num + last_sc - den;
  __syncthreads();
  #pragma unroll
  for (int s = 64; s > 0; s >>= 1) {
    if (b < s) red[b] += red[b + s];
    __syncthreads();
  }
  if (b == 0) out[0] = red[0];
}

extern "C" void kernel_launch(void* const* d_in, const int* in_sizes, int n_in,
                              void* d_out, int out_size, void* d_ws, size_t ws_size,
                              hipStream_t stream)
{
  const float* inp   = (const float*)d_in[0];
  const int*   tags  = (const int*)  d_in[1];
  const int*   mask  = (const int*)  d_in[2];
  const float* trans = (const float*)d_in[3];
  float*       out   = (float*)d_out;

  const int BT = in_sizes[1];
  const int T  = BT / B;   // 2048

  float* pden = (float*)d_ws;            // [CHUNKS][B]
  float* pnum = pden + CHUNKS * B;       // [CHUNKS][B]
  float* pcnt = pnum + CHUNKS * B;       // [CHUNKS][B]

  dim3 grid(B / NB, CHUNKS);
  crf_fwd_chunk<<<grid, 64, 0, stream>>>(inp, tags, mask, trans,
                                         pden, pnum, pcnt, T);
  crf_reduce<<<1, 128, 0, stream>>>(inp, tags, mask, pden, pnum, pcnt, out, T);

  (void)n_in; (void)out_size; (void)ws_size;
}

// Round 15
// 51.174 us; speedup vs baseline: 1.5628x; 1.5628x over previous
//
#include <hip/hip_runtime.h>

// CRF log-likelihood, B=128, T=2048, K=96 on gfx950.
//
// Chunked-parallel forward algorithm (verified R3/R4/R5/R10/R12/R13): logZ
// telescopes into per-chunk Phi differences; exp(trans) contracts normalized
// alpha at Hilbert rate ~0.36/step; chunks warm up from a fabricated init
// WARM=8 steps early (clamped at 0).
//
// Round 15: unified model from R10/R12/R13/R14 counters — fwd wall ==
// total_bytes / ~4 TB/s (an aggregate delivery ceiling for this pattern;
// latency already hidden by R13's DMA ring, burst shape irrelevant per R14).
// So cut BYTES: CHUNKS 128->64, CLEN 16->32 (warm-up redundancy 1.5x->1.25x,
// 147->122 MB). 512 waves can't feed 4 TB/s at depth-0 (R4: 2 TB/s), so the
// R13-verified global_load_lds ring deepens to 8 slabs (48KB, 7-slab lead =
// 42KB/wave in flight; 21.5 MB chip-wide >= R13's 18 MB). Counting discipline
// identical to R13: pre-loop vmcnt(0) drain, constant 6 issues/step with
// dummy-tail, wait vmcnt(42), issue(s+8) hits the just-consumed slab
// ((s+8)&7 == s&7). Mask word widened to u64 (40 steps/chunk).

constexpr int K      = 96;
constexpr int NB     = 16;   // batches per wave (MFMA N dim)
constexpr int CHUNKS = 64;
constexpr int CLEN   = 32;   // accumulated steps per chunk
constexpr int WARM   = 8;    // warm-up steps (clamped at t=0)
constexpr int B      = 128;

typedef __attribute__((ext_vector_type(8))) short bf16x8;
typedef __attribute__((ext_vector_type(4))) float f32x4;

__device__ __forceinline__ unsigned short f2bf(float f) {
  unsigned int b = __float_as_uint(f);
  return (unsigned short)((b + 0x7fff + ((b >> 16) & 1)) >> 16);  // RNE
}
__device__ __forceinline__ float bf2f(unsigned short h) {
  return __uint_as_float(((unsigned int)h) << 16);
}
__device__ __forceinline__ unsigned int cvt_pk_bf16(float lo, float hi) {
  unsigned int r;
  asm volatile("v_cvt_pk_bf16_f32 %0, %1, %2" : "=v"(r) : "v"(lo), "v"(hi));
  return r;
}
__device__ __forceinline__ float lane_bcast(int addr4, float v) {
  return __int_as_float(__builtin_amdgcn_ds_bpermute(addr4, __float_as_int(v)));
}
__device__ __forceinline__ void dma16(const void* g, void* l) {
  __builtin_amdgcn_global_load_lds(
      (const __attribute__((address_space(1))) void*)g,
      (__attribute__((address_space(3))) void*)l, 16, 0, 0);
}

__global__ __launch_bounds__(64, 1) void crf_fwd_chunk(
    const float* __restrict__ inp,    // [B,T,K]
    const int*   __restrict__ tags,   // [B,T]
    const int*   __restrict__ mask,   // [B,T]
    const float* __restrict__ trans,  // [K,K]
    float* __restrict__ pden,         // [CHUNKS][B]
    float* __restrict__ pnum,         // [CHUNKS][B]
    float* __restrict__ pcnt,         // [CHUNKS][B]
    int T)
{
  const int l  = threadIdx.x;
  const int bl = l & 15;     // batch-in-group (= MFMA col)
  const int hi = l >> 4;
  const int g  = blockIdx.x;
  const int c  = blockIdx.y;
  const int b  = g * NB + bl;
  const int bcast = bl * 4;

  const int s_init = max(0, c * CLEN - WARM);
  const int s_A    = c * CLEN;
  const int s_end  = min(c * CLEN + CLEN, T - 1);

  __shared__ unsigned short Xs[NB][104];    // bf16 state, stride 104 shorts
  __shared__ float4 Ering[8][NB * K / 4];   // 8 slabs x 6144 B fp32 emissions
  __shared__ float4 Edummy[64];             // 1 KB tail-DMA sink

  // A fragments: A[row=j][k=i] = exp(trans[i][j]); row=lane&15, k=(lane>>4)*8+e
  bf16x8 A[6][3];
  #pragma unroll
  for (int jt = 0; jt < 6; ++jt) {
    #pragma unroll
    for (int kf = 0; kf < 3; ++kf) {
      const int j = jt * 16 + bl;
      #pragma unroll
      for (int e = 0; e < 8; ++e) {
        const int i = kf * 32 + hi * 8 + e;
        A[jt][kf][e] = (short)f2bf(__expf(trans[i * K + j]));
      }
    }
  }

  const float* ib  = inp  + (size_t)b * T * K;
  const int*   mb  = mask + (size_t)b * T;
  const int*   tgb = tags + (size_t)b * T;

  // ---- init at s_init: x = exp(emit - emit[0]) (plain loads, pre-drain) ----
  {
    const float* i0 = ib + (size_t)s_init * K;
    float4 e0[6];
    #pragma unroll
    for (int jt = 0; jt < 6; ++jt) {
      float4 v = *(const float4*)(i0 + jt * 16 + hi * 4);
      v.x = __expf(v.x); v.y = __expf(v.y); v.z = __expf(v.z); v.w = __expf(v.w);
      e0[jt] = v;
    }
    const float r0  = lane_bcast(bcast, e0[0].x);
    const float inv = 1.0f / r0;
    #pragma unroll
    for (int jt = 0; jt < 6; ++jt) {
      uint2 p;
      p.x = cvt_pk_bf16(e0[jt].x * inv, e0[jt].y * inv);
      p.y = cvt_pk_bf16(e0[jt].z * inv, e0[jt].w * inv);
      *(uint2*)&Xs[bl][jt * 16 + hi * 4] = p;
    }
  }
  double Mref = (double)ib[(size_t)s_init * K];

  bf16x8 Bf[3];
  #pragma unroll
  for (int kf = 0; kf < 3; ++kf)
    Bf[kf] = *(const bf16x8*)&Xs[bl][kf * 32 + hi * 8];

  // mask bits for the whole chunk (<= 40 steps) — 64-bit, loop stays VMEM-free
  unsigned long long mbits = 0;
  const int nsteps = s_end - s_init;
  #pragma unroll
  for (int k2 = 0; k2 < CLEN + WARM; ++k2)
    if (k2 < nsteps)
      mbits |= (mb[s_init + 1 + k2] != 0 ? 1ull : 0ull) << k2;

  // per-lane pre-swizzled DMA source pointers (R13-verified, rule #21).
  // Slab: 16 rows x 384B; physical byte q = p*1024 + l*16; row r = q/384;
  // within-row offset x holds global offset x ^ ((r&7)<<4).
  const char* sp[6];
  #pragma unroll
  for (int p = 0; p < 6; ++p) {
    const int u  = p * 64 + l;            // 16B-chunk index in slab
    const int r  = u / 24;                // batch row (24 x 16B per row)
    const int x  = (u - r * 24) * 16;     // physical byte offset in row
    const int xs = x ^ ((r & 7) << 4);    // inverse-swizzled source offset
    sp[p] = (const char*)(inp + ((size_t)(g * 16 + r) * T + (s_init + 1)) * K) + xs;
  }
  const int swr = (bl & 7) << 4;          // read-side swizzle

  // drain compiler-scheduled VMEM: counted vmcnt is exact from here
  asm volatile("s_waitcnt vmcnt(0)" ::: "memory");
  __builtin_amdgcn_sched_barrier(0);

  auto issue_dma = [&](int s) {
    char* ld = (char*)&Ering[s & 7][0];
    const int off = (s - s_init - 1) * (K * 4);
    #pragma unroll
    for (int p = 0; p < 6; ++p)
      dma16(sp[p] + off, ld + p * 1024);
  };
  auto issue_dummy = [&]() {   // keep issue rate at exactly 6/step in tail
    #pragma unroll
    for (int p = 0; p < 6; ++p)
      dma16(sp[p], (char*)&Edummy[0]);
  };
  auto issue = [&](int s) { if (s <= s_end) issue_dma(s); else issue_dummy(); };

  // prologue: 8 slabs in flight (48 loads)
  issue(s_init + 1); issue(s_init + 2); issue(s_init + 3); issue(s_init + 4);
  issue(s_init + 5); issue(s_init + 6); issue(s_init + 7); issue(s_init + 8);

  auto dostep = [&](int s, bool renorm) {
    // outstanding is always 48 here -> vmcnt(42) == slab s landed
    asm volatile("s_waitcnt vmcnt(42)" ::: "memory");
    __builtin_amdgcn_sched_barrier(0);

    const char* slab = (const char*)&Ering[s & 7][0];
    float4 xe[6];
    #pragma unroll
    for (int jt = 0; jt < 6; ++jt) {
      const float4 e4 =
          *(const float4*)(slab + bl * 384 + ((jt * 64 + hi * 16) ^ swr));
      xe[jt].x = __expf(e4.x); xe[jt].y = __expf(e4.y);
      xe[jt].z = __expf(e4.z); xe[jt].w = __expf(e4.w);
    }
    // xe consumption forced the lgkmcnt drain of the slab reads; safe for the
    // refill (delivery is >> ds_read latency away). Refill pinned here;
    // (s+8)&7 == s&7 -> targets the just-consumed (dead) slab.
    __builtin_amdgcn_sched_barrier(0);
    issue(s + 8);
    __builtin_amdgcn_sched_barrier(0);

    f32x4 acc[6];
    #pragma unroll
    for (int jt = 0; jt < 6; ++jt) {
      f32x4 a = {0.f, 0.f, 0.f, 0.f};
      a = __builtin_amdgcn_mfma_f32_16x16x32_bf16(A[jt][0], Bf[0], a, 0, 0, 0);
      a = __builtin_amdgcn_mfma_f32_16x16x32_bf16(A[jt][1], Bf[1], a, 0, 0, 0);
      a = __builtin_amdgcn_mfma_f32_16x16x32_bf16(A[jt][2], Bf[2], a, 0, 0, 0);
      acc[jt] = a;
    }
    const bool mm = ((mbits >> (s - s_init - 1)) & 1ull) != 0ull;
    float inv = 1.0f;
    if (renorm) {
      const float r = lane_bcast(bcast, acc[0][0]);   // C[0][b]
      inv = 1.0f / r;
      if (mm) Mref += (double)__logf(r);
    }
    if (mm) {   // masked steps keep old x
      #pragma unroll
      for (int jt = 0; jt < 6; ++jt) {
        uint2 p;
        p.x = cvt_pk_bf16(acc[jt][0] * inv * xe[jt].x,
                          acc[jt][1] * inv * xe[jt].y);
        p.y = cvt_pk_bf16(acc[jt][2] * inv * xe[jt].z,
                          acc[jt][3] * inv * xe[jt].w);
        *(uint2*)&Xs[bl][jt * 16 + hi * 4] = p;
      }
    }
    #pragma unroll
    for (int kf = 0; kf < 3; ++kf)
      Bf[kf] = *(const bf16x8*)&Xs[bl][kf * 32 + hi * 8];
  };

  auto phi = [&]() -> double {
    float sum = 0.f;
    #pragma unroll
    for (int u = 0; u < 24; ++u) sum += bf2f(Xs[bl][hi * 24 + u]);
    sum += __shfl_xor(sum, 16);
    sum += __shfl_xor(sum, 32);
    return Mref + (double)__logf(sum);
  };

  double phiA = 0.0;   // c==0: Phi before chunk is 0 by construction
  int s = s_init + 1;
  while (s + 1 <= s_end) {
    dostep(s, false);
    dostep(s + 1, true);
    if (s + 1 == s_A) phiA = phi();   // s_A at offset 8 = pair boundary
    s += 2;
  }
  if (s <= s_end) { dostep(s, true); ++s; }   // odd tail (last chunk: 39)
  const double phiB = phi();

  if (hi == 0) pden[c * B + b] = (float)(phiB - phiA);

  // ---- fused numerator: gold-path terms for t in [c*CLEN, c*CLEN+CLEN) ----
  const int t0 = c * CLEN;
  float nacc = 0.f, mcnt = 0.f;
  #pragma unroll
  for (int k = 0; k < CLEN / 4; ++k) {
    const int t  = t0 + 4 * k + hi;
    const int mt = mb[t];
    mcnt += (float)mt;
    if (t < T - 1) {
      const int tg  = tgb[t];
      const int tg1 = tgb[t + 1];
      nacc = fmaf(trans[tg * K + tg1], (float)mb[t + 1], nacc);
      nacc = fmaf(ib[(size_t)t * K + tg], (float)mt, nacc);
    }
  }
  nacc += __shfl_xor(nacc, 16); nacc += __shfl_xor(nacc, 32);
  mcnt += __shfl_xor(mcnt, 16); mcnt += __shfl_xor(mcnt, 32);
  if (hi == 0) {
    pnum[c * B + b] = nacc;
    pcnt[c * B + b] = mcnt;
  }
}

// ---------------- final reduce: last-tag gather + sum ----------------
__global__ __launch_bounds__(128) void crf_reduce(
    const float* __restrict__ inp, const int* __restrict__ tags,
    const int* __restrict__ mask,
    const float* __restrict__ pden, const float* __restrict__ pnum,
    const float* __restrict__ pcnt, float* __restrict__ out, int T)
{
  const int b = threadIdx.x;   // 128 = B
  float den = 0.f, num = 0.f, cnt = 0.f;
  for (int c = 0; c < CHUNKS; ++c) {
    den += pden[c * B + b];
    num += pnum[c * B + b];
    cnt += pcnt[c * B + b];
  }
  const int last_idx = (int)cnt - 1;
  float last_sc = 0.f;
  if (last_idx >= 0) {
    const int lt = tags[(size_t)b * T + last_idx];
    last_sc = inp[((size_t)b * T + (T - 1)) * K + lt]
            * (float)mask[(size_t)b * T + T - 1];
  }
  __shared__ float red[128];
  red[b] = num + last_sc - den;
  __syncthreads();
  #pragma unroll
  for (int s = 64; s > 0; s >>= 1) {
    if (b < s) red[b] += red[b + s];
    __syncthreads();
  }
  if (b == 0) out[0] = red[0];
}

extern "C" void kernel_launch(void* const* d_in, const int* in_sizes, int n_in,
                              void* d_out, int out_size, void* d_ws, size_t ws_size,
                              hipStream_t stream)
{
  const float* inp   = (const float*)d_in[0];
  const int*   tags  = (const int*)  d_in[1];
  const int*   mask  = (const int*)  d_in[2];
  const float* trans = (const float*)d_in[3];
  float*       out   = (float*)d_out;

  const int BT = in_sizes[1];
  const int T  = BT / B;   // 2048

  float* pden = (float*)d_ws;            // [CHUNKS][B]
  float* pnum = pden + CHUNKS * B;       // [CHUNKS][B]
  float* pcnt = pnum + CHUNKS * B;       // [CHUNKS][B]

  dim3 grid(B / NB, CHUNKS);
  crf_fwd_chunk<<<grid, 64, 0, stream>>>(inp, tags, mask, trans,
                                         pden, pnum, pcnt, T);
  crf_reduce<<<1, 128, 0, stream>>>(inp, tags, mask, pden, pnum, pcnt, out, T);

  (void)n_in; (void)out_size; (void)ws_size;
}

// Round 16
// 43.780 us; speedup vs baseline: 1.8267x; 1.1689x over previous
//
#include <hip/hip_runtime.h>

// CRF log-likelihood, B=128, T=2048, K=96 on gfx950.
//
// Chunked-parallel forward algorithm (verified R3/R4/R5/R10/R11/R12): logZ
// telescopes into per-chunk Phi differences; exp(trans) contracts normalized
// alpha at Hilbert rate ~0.36/step, so chunks warm up from a fabricated init
// WARM steps early. Chunk contribution = Phi(end) - Phi(after-warmup).
//
// Round 16: REVERT to R12 (best verified, 43.9 us). R13 (DMA ring, equal
// geometry): neutral. R14 (page-burst superslabs): regressed (occupancy).
// R15 (fewer bytes at 512 waves): regressed (delivery is concurrency-
// dependent: 512->2.5, 1024->3.7, 2048->4.2 TB/s for this scattered
// pattern). R12's 147MB @ 1024 waves sits on the measured optimum of
// bytes/delivery; FETCH ~= compulsory 94MB. This is the roofline candidate.

constexpr int K      = 96;
constexpr int NB     = 16;   // batches per wave (MFMA N dim)
constexpr int CHUNKS = 128;
constexpr int CLEN   = 16;   // accumulated steps per chunk
constexpr int WARM   = 8;    // warm-up steps (clamped at t=0)
constexpr int B      = 128;

typedef __attribute__((ext_vector_type(8))) short bf16x8;
typedef __attribute__((ext_vector_type(4))) float f32x4;

__device__ __forceinline__ unsigned short f2bf(float f) {
  unsigned int b = __float_as_uint(f);
  return (unsigned short)((b + 0x7fff + ((b >> 16) & 1)) >> 16);  // RNE
}
__device__ __forceinline__ float bf2f(unsigned short h) {
  return __uint_as_float(((unsigned int)h) << 16);
}
__device__ __forceinline__ unsigned int cvt_pk_bf16(float lo, float hi) {
  unsigned int r;
  asm volatile("v_cvt_pk_bf16_f32 %0, %1, %2" : "=v"(r) : "v"(lo), "v"(hi));
  return r;
}
__device__ __forceinline__ float lane_bcast(int addr4, float v) {
  return __int_as_float(__builtin_amdgcn_ds_bpermute(addr4, __float_as_int(v)));
}

__global__ __launch_bounds__(64, 1) void crf_fwd_chunk(
    const float* __restrict__ inp,    // [B,T,K]
    const int*   __restrict__ tags,   // [B,T]
    const int*   __restrict__ mask,   // [B,T]
    const float* __restrict__ trans,  // [K,K]
    float* __restrict__ pden,         // [CHUNKS][B]
    float* __restrict__ pnum,         // [CHUNKS][B]
    float* __restrict__ pcnt,         // [CHUNKS][B]
    int T)
{
  const int l  = threadIdx.x;
  const int bl = l & 15;     // batch-in-group (= MFMA col)
  const int hi = l >> 4;
  const int g  = blockIdx.x;
  const int c  = blockIdx.y;
  const int b  = g * NB + bl;
  const int bcast = bl * 4;

  const int s_init = max(0, c * CLEN - WARM);
  const int s_A    = c * CLEN;
  const int s_end  = min(c * CLEN + CLEN, T - 1);

  __shared__ unsigned short Xs[NB][104];   // bf16 state, stride 104 shorts

  // A fragments: A[row=j][k=i] = exp(trans[i][j]); row=lane&15, k=(lane>>4)*8+e
  bf16x8 A[6][3];
  #pragma unroll
  for (int jt = 0; jt < 6; ++jt) {
    #pragma unroll
    for (int kf = 0; kf < 3; ++kf) {
      const int j = jt * 16 + bl;
      #pragma unroll
      for (int e = 0; e < 8; ++e) {
        const int i = kf * 32 + hi * 8 + e;
        A[jt][kf][e] = (short)f2bf(__expf(trans[i * K + j]));
      }
    }
  }

  const float* ib  = inp  + (size_t)b * T * K;
  const int*   mb  = mask + (size_t)b * T;
  const int*   tgb = tags + (size_t)b * T;

  // ---- init at s_init: x = exp(emit - emit[0]) (exact for s_init==0) ----
  {
    const float* i0 = ib + (size_t)s_init * K;
    float4 e0[6];
    #pragma unroll
    for (int jt = 0; jt < 6; ++jt) {
      float4 v = *(const float4*)(i0 + jt * 16 + hi * 4);
      v.x = __expf(v.x); v.y = __expf(v.y); v.z = __expf(v.z); v.w = __expf(v.w);
      e0[jt] = v;
    }
    const float r0  = lane_bcast(bcast, e0[0].x);
    const float inv = 1.0f / r0;
    #pragma unroll
    for (int jt = 0; jt < 6; ++jt) {
      uint2 p;
      p.x = cvt_pk_bf16(e0[jt].x * inv, e0[jt].y * inv);
      p.y = cvt_pk_bf16(e0[jt].z * inv, e0[jt].w * inv);
      *(uint2*)&Xs[bl][jt * 16 + hi * 4] = p;
    }
  }
  double Mref = (double)ib[(size_t)s_init * K];

  bf16x8 Bf[3];
  #pragma unroll
  for (int kf = 0; kf < 3; ++kf)
    Bf[kf] = *(const bf16x8*)&Xs[bl][kf * 32 + hi * 8];

  // 4 named buffers (R5-verified loop shape)
  float4 A0[6], A1[6], B0[6], B1[6];
  int    mA0 = 0, mA1 = 0, mB0 = 0, mB1 = 0;

  auto loadE = [&](int s, float4 (&e)[6], int& m) {
    if (s <= s_end) {
      #pragma unroll
      for (int jt = 0; jt < 6; ++jt)
        e[jt] = *(const float4*)(ib + (size_t)s * K + jt * 16 + hi * 4);
      m = mb[s];
    }
  };

  // one step; renorm only when flagged (Phi = Mref + log sum x is
  // scale-correct at any time; renorm-every-2 keeps x within fp32/bf16 range)
  auto dostep = [&](float4 (&ebuf)[6], int msl, bool renorm) {
    f32x4 acc[6];
    #pragma unroll
    for (int jt = 0; jt < 6; ++jt) {
      f32x4 a = {0.f, 0.f, 0.f, 0.f};
      a = __builtin_amdgcn_mfma_f32_16x16x32_bf16(A[jt][0], Bf[0], a, 0, 0, 0);
      a = __builtin_amdgcn_mfma_f32_16x16x32_bf16(A[jt][1], Bf[1], a, 0, 0, 0);
      a = __builtin_amdgcn_mfma_f32_16x16x32_bf16(A[jt][2], Bf[2], a, 0, 0, 0);
      acc[jt] = a;
    }
    const bool mm = msl != 0;
    float inv = 1.0f;
    if (renorm) {
      const float r = lane_bcast(bcast, acc[0][0]);   // C[0][b]
      inv = 1.0f / r;
      if (mm) Mref += (double)__logf(r);
    }
    if (mm) {   // masked steps keep old x
      #pragma unroll
      for (int jt = 0; jt < 6; ++jt) {
        const float4 e4 = ebuf[jt];
        uint2 p;
        p.x = cvt_pk_bf16(acc[jt][0] * inv * __expf(e4.x),
                          acc[jt][1] * inv * __expf(e4.y));
        p.y = cvt_pk_bf16(acc[jt][2] * inv * __expf(e4.z),
                          acc[jt][3] * inv * __expf(e4.w));
        *(uint2*)&Xs[bl][jt * 16 + hi * 4] = p;
      }
    }
    #pragma unroll
    for (int kf = 0; kf < 3; ++kf)
      Bf[kf] = *(const bf16x8*)&Xs[bl][kf * 32 + hi * 8];
  };

  auto phi = [&]() -> double {
    float sum = 0.f;
    #pragma unroll
    for (int u = 0; u < 24; ++u) sum += bf2f(Xs[bl][hi * 24 + u]);
    sum += __shfl_xor(sum, 16);
    sum += __shfl_xor(sum, 32);
    return Mref + (double)__logf(sum);
  };

  loadE(s_init + 1, A0, mA0); loadE(s_init + 2, A1, mA1);
  loadE(s_init + 3, B0, mB0); loadE(s_init + 4, B1, mB1);

  double phiA = 0.0;   // c==0: Phi before chunk is 0 by construction
  int s = s_init + 1;
  while (s + 3 <= s_end) {
    dostep(A0, mA0, false);
    dostep(A1, mA1, true);
    if (s + 1 == s_A) phiA = phi();
    loadE(s + 4, A0, mA0); loadE(s + 5, A1, mA1);
    dostep(B0, mB0, false);
    dostep(B1, mB1, true);
    if (s + 3 == s_A) phiA = phi();
    loadE(s + 6, B0, mB0); loadE(s + 7, B1, mB1);
    s += 4;
  }
  // tails: remaining r = s_end-s+1 in {0,2,3} for this geometry (r=1 guarded)
  if (s + 1 <= s_end) {
    dostep(A0, mA0, false);
    dostep(A1, mA1, true);
    if (s + 1 == s_A) phiA = phi();
    s += 2;
    if (s <= s_end) { dostep(B0, mB0, true); ++s; }
  } else if (s <= s_end) {
    dostep(A0, mA0, true);
    ++s;
  }
  const double phiB = phi();

  if (hi == 0) pden[c * B + b] = (float)(phiB - phiA);

  // ---- fused numerator: gold-path terms for t in [c*CLEN, c*CLEN+CLEN) ----
  const int t0 = c * CLEN;
  float nacc = 0.f, mcnt = 0.f;
  #pragma unroll
  for (int k = 0; k < CLEN / 4; ++k) {
    const int t  = t0 + 4 * k + hi;
    const int mt = mb[t];
    mcnt += (float)mt;
    if (t < T - 1) {
      const int tg  = tgb[t];
      const int tg1 = tgb[t + 1];
      nacc = fmaf(trans[tg * K + tg1], (float)mb[t + 1], nacc);
      nacc = fmaf(ib[(size_t)t * K + tg], (float)mt, nacc);
    }
  }
  nacc += __shfl_xor(nacc, 16); nacc += __shfl_xor(nacc, 32);
  mcnt += __shfl_xor(mcnt, 16); mcnt += __shfl_xor(mcnt, 32);
  if (hi == 0) {
    pnum[c * B + b] = nacc;
    pcnt[c * B + b] = mcnt;
  }
}

// ---------------- final reduce: last-tag gather + sum ----------------
__global__ __launch_bounds__(128) void crf_reduce(
    const float* __restrict__ inp, const int* __restrict__ tags,
    const int* __restrict__ mask,
    const float* __restrict__ pden, const float* __restrict__ pnum,
    const float* __restrict__ pcnt, float* __restrict__ out, int T)
{
  const int b = threadIdx.x;   // 128 = B
  float den = 0.f, num = 0.f, cnt = 0.f;
  for (int c = 0; c < CHUNKS; ++c) {
    den += pden[c * B + b];
    num += pnum[c * B + b];
    cnt += pcnt[c * B + b];
  }
  const int last_idx = (int)cnt - 1;
  float last_sc = 0.f;
  if (last_idx >= 0) {
    const int lt = tags[(size_t)b * T + last_idx];
    last_sc = inp[((size_t)b * T + (T - 1)) * K + lt]
            * (float)mask[(size_t)b * T + T - 1];
  }
  __shared__ float red[128];
  red[b] = num + last_sc - den;
  __syncthreads();
  #pragma unroll
  for (int s = 64; s > 0; s >>= 1) {
    if (b < s) red[b] += red[b + s];
    __syncthreads();
  }
  if (b == 0) out[0] = red[0];
}

extern "C" void kernel_launch(void* const* d_in, const int* in_sizes, int n_in,
                              void* d_out, int out_size, void* d_ws, size_t ws_size,
                              hipStream_t stream)
{
  const float* inp   = (const float*)d_in[0];
  const int*   tags  = (const int*)  d_in[1];
  const int*   mask  = (const int*)  d_in[2];
  const float* trans = (const float*)d_in[3];
  float*       out   = (float*)d_out;

  const int BT = in_sizes[1];
  const int T  = BT / B;   // 2048

  float* pden = (float*)d_ws;            // [CHUNKS][B]
  float* pnum = pden + CHUNKS * B;       // [CHUNKS][B]
  float* pcnt = pnum + CHUNKS * B;       // [CHUNKS][B]

  dim3 grid(B / NB, CHUNKS);
  crf_fwd_chunk<<<grid, 64, 0, stream>>>(inp, tags, mask, trans,
                                         pden, pnum, pcnt, T);
  crf_reduce<<<1, 128, 0, stream>>>(inp, tags, mask, pden, pnum, pcnt, out, T);

  (void)n_in; (void)out_size; (void)ws_size;
}